// Round 24
// baseline (181.980 us; speedup 1.0000x reference)
//
#include <hip/hip_runtime.h>
#include <hip/hip_bf16.h>
#include <math.h>

#define NTOK   4096      // B*S
#define DMODEL 1024
#define DFFN   2048
#define NEXP   8         // FFN experts
#define ETOT   12        // total experts (8 FFN + 4 zero)
#define MAXA   8192      // max assignments (NTOK * TOP_K)
#define WL1MAX (MAXA / 128 + NEXP)   // 72 worst-case m-blocks, BM=128
#define WL2MAX (MAXA / 128 + NEXP)   // 72 worst-case m-blocks, BM=128
#define G1GRID (WL1MAX * (DFFN / 128))   // 1152 GEMM1 blocks
#define CVT_N8 (NEXP * DMODEL * DFFN / 8)        // 2,097,152 8-float groups
#define CVT_PER ((CVT_N8 + G1GRID - 1) / G1GRID) // 1821 groups per block

typedef short          bf16x8   __attribute__((ext_vector_type(8)));
typedef float          f32x4    __attribute__((ext_vector_type(4)));
typedef unsigned short ushort8v __attribute__((ext_vector_type(8)));

__device__ __forceinline__ unsigned short f2bf(float f) {
  unsigned int u = __float_as_uint(f);
  unsigned int r = (u + 0x7fffu + ((u >> 16) & 1u)) >> 16;  // RNE
  return (unsigned short)r;
}

// scalar bf16 cast — compiler fuses pairs into v_cvt_pk_bf16_f32 (m240)
__device__ __forceinline__ unsigned short f2bfh(float f) {
  __hip_bfloat16 h = __float2bfloat16(f);
  return __builtin_bit_cast(unsigned short, h);
}

#define G2L16(g, l)                                                        \
  __builtin_amdgcn_global_load_lds(                                        \
      (const __attribute__((address_space(1))) void*)(g),                  \
      (__attribute__((address_space(3))) void*)(l), 16, 0, 0)

// per-block w2->W2b slice convert: disjoint [id*CVT_PER, (id+1)*CVT_PER)
__device__ __forceinline__ void cvt_slice(int id, int tid,
                                          const float* __restrict__ src,
                                          unsigned short* __restrict__ dst) {
  int lo = id * CVT_PER;
  int hi = lo + CVT_PER;
  if (hi > CVT_N8) hi = CVT_N8;
  const float4* p = (const float4*)src;
  for (int i = lo + tid; i < hi; i += 256) {
    float4 v0 = p[2 * (size_t)i], v1 = p[2 * (size_t)i + 1];
    ushort4 u0, u1;
    u0.x = f2bf(v0.x); u0.y = f2bf(v0.y); u0.z = f2bf(v0.z); u0.w = f2bf(v0.w);
    u1.x = f2bf(v1.x); u1.y = f2bf(v1.y); u1.z = f2bf(v1.z); u1.w = f2bf(v1.w);
    ((ushort4*)dst)[2 * (size_t)i]     = u0;
    ((ushort4*)dst)[2 * (size_t)i + 1] = u1;
  }
}

// ---- routing phase A; also emits Xb (bf16 of x) as it reads x ----------
__launch_bounds__(256)
__global__ void logits_kernel(const float* __restrict__ x,
                              const float* __restrict__ gw,
                              const float* __restrict__ eb,
                              float* __restrict__ logits,
                              unsigned short* __restrict__ Xb) {
  __shared__ float gws[ETOT * DMODEL];   // 48 KB
  int tid = threadIdx.x;
  const float4* gw4 = (const float4*)gw;
  float4* gws4 = (float4*)gws;
  #pragma unroll
  for (int i = 0; i < (ETOT * DMODEL / 4) / 256; i++)
    gws4[tid + i * 256] = gw4[tid + i * 256];
  __syncthreads();

  int sub = tid >> 4;
  int l16 = tid & 15;
  int tok = blockIdx.x * 16 + sub;
  const float4* xr = (const float4*)(x + (size_t)tok * DMODEL);
  ushort4* xbr = (ushort4*)(Xb + (size_t)tok * DMODEL);

  float s[ETOT] = {};
  #pragma unroll
  for (int j = 0; j < 16; j++) {
    float4 xv = xr[l16 + j * 16];
    ushort4 u; u.x = f2bf(xv.x); u.y = f2bf(xv.y); u.z = f2bf(xv.z); u.w = f2bf(xv.w);
    xbr[l16 + j * 16] = u;
    #pragma unroll
    for (int e = 0; e < ETOT; e++) {
      float4 g = gws4[e * (DMODEL / 4) + l16 + j * 16];
      s[e] += xv.x * g.x + xv.y * g.y + xv.z * g.z + xv.w * g.w;
    }
  }
  #pragma unroll
  for (int e = 0; e < ETOT; e++) {
    #pragma unroll
    for (int m = 8; m >= 1; m >>= 1) s[e] += __shfl_xor(s[e], m, 64);
  }
  if (l16 == 0) {
    #pragma unroll
    for (int e = 0; e < ETOT; e++)
      logits[(size_t)tok * ETOT + e] = s[e] + eb[e];
  }
}

// ---------------- routing phase B: top-2, softmax, counts ----------------
__global__ void topk_kernel(const float* __restrict__ logits,
                            int* __restrict__ cnt,
                            int* __restrict__ choice,
                            float* __restrict__ chw,
                            float* __restrict__ wz) {
  int t = blockIdx.x * blockDim.x + threadIdx.x;
  if (t >= NTOK) return;
  const float4* lr = (const float4*)(logits + (size_t)t * ETOT);
  float4 a = lr[0], b = lr[1], c = lr[2];
  float lg[ETOT] = { a.x, a.y, a.z, a.w, b.x, b.y, b.z, b.w, c.x, c.y, c.z, c.w };
  int i1 = 0; float m1 = lg[0];
  #pragma unroll
  for (int e = 1; e < ETOT; e++) if (lg[e] > m1) { m1 = lg[e]; i1 = e; }
  int i2 = -1; float m2 = -3.4e38f;
  #pragma unroll
  for (int e = 0; e < ETOT; e++) { if (e == i1) continue; if (lg[e] > m2) { m2 = lg[e]; i2 = e; } }
  float ex = expf(m2 - m1);
  float w0 = 1.f / (1.f + ex);
  float w1 = ex / (1.f + ex);
  int ee[2] = { i1, i2 };
  float ww[2] = { w0, w1 };
  float z = 0.f;
  #pragma unroll
  for (int k = 0; k < 2; k++) {
    choice[t * 2 + k] = ee[k];
    chw[t * 2 + k]    = ww[k];
    if (ee[k] < NEXP) atomicAdd(&cnt[ee[k]], 1);
    else              z += ww[k];
  }
  wz[t] = z;
}

// -------- scan + dense worklists: (expert|mb<<8) per working m-block ------
__global__ void scan_kernel(const int* __restrict__ cnt,
                            int* __restrict__ offs,
                            int* __restrict__ cursor,
                            int* __restrict__ wl1, int* __restrict__ nw1,
                            int* __restrict__ wl2, int* __restrict__ nw2) {
  if (threadIdx.x == 0) {
    int a = 0;
    for (int e = 0; e < NEXP; e++) { offs[e] = a; cursor[e] = a; a += cnt[e]; }
    int n1 = 0, n2 = 0;
    for (int e = 0; e < NEXP; e++) {
      int c = cnt[e];
      for (int mb = 0; mb * 128 < c; mb++) wl1[n1++] = e | (mb << 8);
      for (int mb = 0; mb * 128 < c; mb++) wl2[n2++] = e | (mb << 8);
    }
    *nw1 = n1; *nw2 = n2;
  }
}

// ---------------- slot assignment (order nondeterministic, values not) ----
__global__ void assign_kernel(const int* __restrict__ choice,
                              int* __restrict__ cursor,
                              int* __restrict__ a_row,
                              int* __restrict__ tok_list) {
  int t = blockIdx.x * blockDim.x + threadIdx.x;
  if (t >= NTOK) return;
  #pragma unroll
  for (int k = 0; k < 2; k++) {
    int e = choice[2 * t + k];
    if (e < NEXP) {
      int pos = atomicAdd(&cursor[e], 1);
      a_row[2 * t + k] = pos;
      tok_list[pos] = t;
    } else {
      a_row[2 * t + k] = -1;
    }
  }
}

// -------- GEMM variant A (r8, replay-proven): all-bf16, async staging -----
// Used for GEMM2: A = H rows, B = W2b (pre-converted bf16).
template <int BM, int NDIM, int KDIM, bool SILU, bool AGATHER>
__launch_bounds__(256)
__global__ void ffn_gemm_bf(const unsigned short* __restrict__ Abf,
                            const unsigned short* __restrict__ Bw,
                            const int* __restrict__ cnt,
                            const int* __restrict__ offs,
                            const int* __restrict__ tok_list,
                            const int* __restrict__ wl,
                            const int* __restrict__ nwork,
                            unsigned short* __restrict__ OutBf,
                            float* __restrict__ OutF) {
  constexpr int NB = NDIM / 128;
  constexpr int MI = BM / 32;
  constexpr int AJ = BM / 64;
  int id = blockIdx.x;
  int nb = id & (NB - 1);
  int wb = id / NB;
  if (wb >= *nwork) return;
  int w  = wl[wb];
  int e  = w & 255;
  int mb = w >> 8;
  int count = cnt[e];
  int m0 = mb * BM;
  int off = offs[e];
  int n0 = nb * 128;
  const unsigned short* B = Bw + (size_t)e * NDIM * KDIM;

  __shared__ unsigned short lA[2][BM * 32];
  __shared__ unsigned short lB[2][128 * 32];

  int tid  = threadIdx.x;
  int lane = tid & 63;
  int wv = tid >> 6;
  int wm = wv >> 1, wn = wv & 1;
  int lr = lane & 15, lk8 = (lane >> 4) * 8;

  int srow = tid >> 2;
  int scol = (tid & 3) * 8;
  const unsigned short* aSrc[AJ];
  const unsigned short* bSrc[2];
  #pragma unroll
  for (int j = 0; j < AJ; j++) {
    int rr = m0 + j * 64 + srow;
    if (rr >= count) rr = count - 1;
    if (AGATHER) aSrc[j] = Abf + (size_t)tok_list[off + rr] * KDIM + scol;
    else         aSrc[j] = Abf + (size_t)(off + rr) * KDIM + scol;
  }
  #pragma unroll
  for (int j = 0; j < 2; j++)
    bSrc[j] = B + (size_t)(n0 + j * 64 + srow) * KDIM + scol;

  f32x4 acc[MI][4] = {};

#define STAGE(b, kk)                                                        \
  do {                                                                      \
    int kb_ = (kk) * 32;                                                    \
    _Pragma("unroll")                                                       \
    for (int j = 0; j < AJ; j++) G2L16(aSrc[j] + kb_, &lA[b][j * 2048 + tid * 8]); \
    _Pragma("unroll")                                                       \
    for (int j = 0; j < 2; j++)  G2L16(bSrc[j] + kb_, &lB[b][j * 2048 + tid * 8]); \
  } while (0)

#define COMPUTE(b)                                                          \
  do {                                                                      \
    bf16x8 af[MI], bq[4];                                                   \
    _Pragma("unroll")                                                       \
    for (int mi = 0; mi < MI; mi++)                                         \
      af[mi] = *(const bf16x8*)&lA[b][(wm * (BM / 2) + mi * 16 + lr) * 32 + lk8]; \
    _Pragma("unroll")                                                       \
    for (int ni = 0; ni < 4; ni++)                                          \
      bq[ni] = *(const bf16x8*)&lB[b][(wn * 64 + ni * 16 + lr) * 32 + lk8]; \
    _Pragma("unroll")                                                       \
    for (int mi = 0; mi < MI; mi++)                                         \
      _Pragma("unroll")                                                     \
      for (int ni = 0; ni < 4; ni++)                                        \
        acc[mi][ni] = __builtin_amdgcn_mfma_f32_16x16x32_bf16(af[mi], bq[ni], acc[mi][ni], 0, 0, 0); \
  } while (0)

  constexpr int NK = KDIM / 32;   // even
  STAGE(0, 0);
  __syncthreads();
  #pragma unroll 1
  for (int kk = 0; kk < NK; kk += 2) {
    if (kk + 1 < NK) STAGE(1, kk + 1);
    COMPUTE(0);
    __syncthreads();
    if (kk + 1 < NK) {
      if (kk + 2 < NK) STAGE(0, kk + 2);
      COMPUTE(1);
      __syncthreads();
    }
  }
#undef STAGE
#undef COMPUTE

  int rb = (lane >> 4) * 4;
  #pragma unroll
  for (int mi = 0; mi < MI; mi++) {
    #pragma unroll
    for (int i = 0; i < 4; i++) {
      int grow = m0 + wm * (BM / 2) + mi * 16 + rb + i;
      if (grow >= count) continue;
      #pragma unroll
      for (int ni = 0; ni < 4; ni++) {
        int gcol = n0 + wn * 64 + ni * 16 + lr;
        float v = acc[mi][ni][i];
        if (SILU) {
          float s = v * __builtin_amdgcn_rcpf(
                        1.f + __builtin_amdgcn_exp2f(-v * 1.44269504088896f));
          OutBf[(size_t)(off + grow) * NDIM + gcol] = f2bf(s);
        } else {
          OutF[(size_t)(off + grow) * NDIM + gcol] = v;
        }
      }
    }
  }
}

// -------- GEMM1 fused: in-kernel w1 convert + DISTRIBUTED w2-cvt ---------
// Each of the 1152 blocks converts a disjoint w2 slice (CVT_PER groups)
// after its GEMM work. Early-exit blocks (~40% of ids: holes/past-nwork)
// convert immediately — overlapping the working GEMM blocks; workers
// append theirs at staggered retirement. Grid unchanged -> no residency
// displacement (r21's failure); not tail-serialized (r18's failure).
template <int BM, int NDIM, int KDIM, bool SILU, bool AGATHER>
__launch_bounds__(256)
__global__ void ffn_gemm_cv_fused(const unsigned short* __restrict__ Abf,
                                  const float* __restrict__ BwF,
                                  const int* __restrict__ cnt,
                                  const int* __restrict__ offs,
                                  const int* __restrict__ tok_list,
                                  const int* __restrict__ wl,
                                  const int* __restrict__ nwork,
                                  unsigned short* __restrict__ OutBf,
                                  float* __restrict__ OutF,
                                  const float* __restrict__ cvt_src,
                                  unsigned short* __restrict__ cvt_dst) {
  constexpr int NB = NDIM / 128;
  constexpr int MI = BM / 32;
  constexpr int AJ = BM / 64;
  int id = blockIdx.x;
  int tid  = threadIdx.x;
  int nb = id & (NB - 1);
  int wb = id / NB;
  if (wb >= *nwork) {
    cvt_slice(id, tid, cvt_src, cvt_dst);
    return;
  }
  int w  = wl[wb];
  int e  = w & 255;
  int mb = w >> 8;
  int count = cnt[e];
  int m0 = mb * BM;
  int off = offs[e];
  int n0 = nb * 128;
  const float* B = BwF + (size_t)e * NDIM * KDIM;

  __shared__ unsigned short lA[2][BM * 32];
  __shared__ unsigned short lB[2][128 * 32];

  int lane = tid & 63;
  int wv = tid >> 6;
  int wm = wv >> 1, wn = wv & 1;
  int lr = lane & 15, lk8 = (lane >> 4) * 8;

  int srow = tid >> 2;
  int scol = (tid & 3) * 8;
  const unsigned short* aSrc[AJ];
  const float* bSrc[2];
  #pragma unroll
  for (int j = 0; j < AJ; j++) {
    int rr = m0 + j * 64 + srow;
    if (rr >= count) rr = count - 1;
    if (AGATHER) aSrc[j] = Abf + (size_t)tok_list[off + rr] * KDIM + scol;
    else         aSrc[j] = Abf + (size_t)(off + rr) * KDIM + scol;
  }
  #pragma unroll
  for (int j = 0; j < 2; j++)
    bSrc[j] = B + (size_t)(n0 + j * 64 + srow) * KDIM + scol;

  f32x4 acc[MI][4] = {};
  f32x4 breg[2][2];

#define STAGEA(b, kk)                                                       \
  do {                                                                      \
    int kb_ = (kk) * 32;                                                    \
    _Pragma("unroll")                                                       \
    for (int j = 0; j < AJ; j++) G2L16(aSrc[j] + kb_, &lA[b][j * 2048 + tid * 8]); \
  } while (0)

#define LOADB(kk)                                                           \
  do {                                                                      \
    int kb_ = (kk) * 32;                                                    \
    _Pragma("unroll")                                                       \
    for (int j = 0; j < 2; j++) {                                           \
      const f32x4* p_ = (const f32x4*)(bSrc[j] + kb_);                      \
      breg[j][0] = p_[0]; breg[j][1] = p_[1];                               \
    }                                                                       \
  } while (0)

#define WRITEB(b)                                                           \
  do {                                                                      \
    _Pragma("unroll")                                                       \
    for (int j = 0; j < 2; j++) {                                           \
      ushort8v u_;                                                          \
      u_[0] = f2bfh(breg[j][0][0]); u_[1] = f2bfh(breg[j][0][1]);           \
      u_[2] = f2bfh(breg[j][0][2]); u_[3] = f2bfh(breg[j][0][3]);           \
      u_[4] = f2bfh(breg[j][1][0]); u_[5] = f2bfh(breg[j][1][1]);           \
      u_[6] = f2bfh(breg[j][1][2]); u_[7] = f2bfh(breg[j][1][3]);           \
      *(ushort8v*)&lB[b][j * 2048 + tid * 8] = u_;                          \
    }                                                                       \
  } while (0)

#define COMPUTE(b)                                                          \
  do {                                                                      \
    bf16x8 af[MI], bq[4];                                                   \
    _Pragma("unroll")                                                       \
    for (int mi = 0; mi < MI; mi++)                                         \
      af[mi] = *(const bf16x8*)&lA[b][(wm * (BM / 2) + mi * 16 + lr) * 32 + lk8]; \
    _Pragma("unroll")                                                       \
    for (int ni = 0; ni < 4; ni++)                                          \
      bq[ni] = *(const bf16x8*)&lB[b][(wn * 64 + ni * 16 + lr) * 32 + lk8]; \
    _Pragma("unroll")                                                       \
    for (int mi = 0; mi < MI; mi++)                                         \
      _Pragma("unroll")                                                     \
      for (int ni = 0; ni < 4; ni++)                                        \
        acc[mi][ni] = __builtin_amdgcn_mfma_f32_16x16x32_bf16(af[mi], bq[ni], acc[mi][ni], 0, 0, 0); \
  } while (0)

  constexpr int NK = KDIM / 32;   // even
  LOADB(0);
  STAGEA(0, 0);
  WRITEB(0);
  __syncthreads();
  #pragma unroll 1
  for (int kk = 0; kk < NK; kk += 2) {
    if (kk + 1 < NK) { LOADB(kk + 1); STAGEA(1, kk + 1); }
    COMPUTE(0);
    if (kk + 1 < NK) WRITEB(1);
    __syncthreads();
    if (kk + 1 < NK) {
      if (kk + 2 < NK) { LOADB(kk + 2); STAGEA(0, kk + 2); }
      COMPUTE(1);
      if (kk + 2 < NK) WRITEB(0);
      __syncthreads();
    }
  }
#undef STAGEA
#undef LOADB
#undef WRITEB
#undef COMPUTE

  int rb = (lane >> 4) * 4;
  #pragma unroll
  for (int mi = 0; mi < MI; mi++) {
    #pragma unroll
    for (int i = 0; i < 4; i++) {
      int grow = m0 + wm * (BM / 2) + mi * 16 + rb + i;
      if (grow >= count) continue;
      #pragma unroll
      for (int ni = 0; ni < 4; ni++) {
        int gcol = n0 + wn * 64 + ni * 16 + lr;
        float v = acc[mi][ni][i];
        if (SILU) {
          float s = v * __builtin_amdgcn_rcpf(
                        1.f + __builtin_amdgcn_exp2f(-v * 1.44269504088896f));
          OutBf[(size_t)(off + grow) * NDIM + gcol] = f2bf(s);
        } else {
          OutF[(size_t)(off + grow) * NDIM + gcol] = v;
        }
      }
    }
  }
  // distributed w2-cvt: this block's slice, after its GEMM work
  cvt_slice(id, tid, cvt_src, cvt_dst);
}

// ---------------- final combine: out = wz*x + sum_k w_k * Y[row_k] --------
__global__ void combine_kernel(const float* __restrict__ x,
                               const float* __restrict__ Y,
                               const int* __restrict__ a_row,
                               const float* __restrict__ chw,
                               const float* __restrict__ wz,
                               float* __restrict__ out) {
  int t = blockIdx.x;
  int d = threadIdx.x * 4;
  const float4 xv = *(const float4*)&x[(size_t)t * DMODEL + d];
  float z = wz[t];
  float4 o; o.x = z * xv.x; o.y = z * xv.y; o.z = z * xv.z; o.w = z * xv.w;
  #pragma unroll
  for (int k = 0; k < 2; k++) {
    int r = a_row[2 * t + k];
    if (r >= 0) {
      float w = chw[2 * t + k];
      const float4 yv = *(const float4*)&Y[(size_t)r * DMODEL + d];
      o.x += w * yv.x; o.y += w * yv.y; o.z += w * yv.z; o.w += w * yv.w;
    }
  }
  *(float4*)&out[(size_t)t * DMODEL + d] = o;
}

extern "C" void kernel_launch(void* const* d_in, const int* in_sizes, int n_in,
                              void* d_out, int out_size, void* d_ws, size_t ws_size,
                              hipStream_t stream) {
  const float* x  = (const float*)d_in[0];   // (2,2048,1024)
  const float* gw = (const float*)d_in[1];   // (12,1024)
  const float* eb = (const float*)d_in[2];   // (12,)
  const float* w1 = (const float*)d_in[3];   // (8,2048,1024)
  const float* w2 = (const float*)d_in[4];   // (8,1024,2048)
  float* out = (float*)d_out;

  char* ws = (char*)d_ws;
  size_t o = 0;
  int*   cnt     = (int*)(ws + o);  o += 8 * sizeof(int);
  int*   offs    = (int*)(ws + o);  o += 8 * sizeof(int);
  int*   cursor  = (int*)(ws + o);  o += 8 * sizeof(int);
  int*   nw1     = (int*)(ws + o);  o += sizeof(int);
  int*   nw2     = (int*)(ws + o);  o += sizeof(int);
  o = (o + 255) & ~(size_t)255;
  int*   wl1     = (int*)(ws + o);  o += WL1MAX * sizeof(int);
  int*   wl2     = (int*)(ws + o);  o += WL2MAX * sizeof(int);
  o = (o + 255) & ~(size_t)255;
  int*   choice  = (int*)(ws + o);  o += (size_t)2 * NTOK * sizeof(int);
  float* chw     = (float*)(ws + o); o += (size_t)2 * NTOK * sizeof(float);
  float* wzv     = (float*)(ws + o); o += (size_t)NTOK * sizeof(float);
  int*   a_row   = (int*)(ws + o);  o += (size_t)2 * NTOK * sizeof(int);
  int*   tok     = (int*)(ws + o);  o += (size_t)MAXA * sizeof(int);
  float* logits  = (float*)(ws + o); o += (size_t)NTOK * ETOT * sizeof(float);
  o = (o + 255) & ~(size_t)255;
  unsigned short* Xb  = (unsigned short*)(ws + o); o += (size_t)NTOK * DMODEL * sizeof(unsigned short);
  unsigned short* W2b = (unsigned short*)(ws + o); o += (size_t)NEXP * DMODEL * DFFN * sizeof(unsigned short);
  unsigned short* H   = (unsigned short*)(ws + o); o += (size_t)MAXA * DFFN * sizeof(unsigned short);
  float*          Y   = (float*)(ws + o);          o += (size_t)MAXA * DMODEL * sizeof(float);

  hipMemsetAsync(cnt, 0, 8 * sizeof(int), stream);

  // logits also emits Xb (bf16 of x). w1 converted inside GEMM1; w2 by the
  // distributed per-block cvt slices of GEMM1's dispatch (consumer: GEMM2).
  logits_kernel<<<dim3(NTOK / 16), dim3(256), 0, stream>>>(x, gw, eb, logits, Xb);
  topk_kernel<<<dim3(NTOK / 256), dim3(256), 0, stream>>>(logits, cnt, choice, chw, wzv);
  scan_kernel<<<dim3(1), dim3(64), 0, stream>>>(cnt, offs, cursor, wl1, nw1, wl2, nw2);
  assign_kernel<<<dim3(NTOK / 256), dim3(256), 0, stream>>>(choice, cursor, a_row, tok);

  // GEMM1 (+ distributed w2 cvt): H = silu(Xb @ bf16(w1)^T); N=2048, K=1024
  ffn_gemm_cv_fused<128, DFFN, DMODEL, true, true>
      <<<dim3(G1GRID), dim3(256), 0, stream>>>(
      Xb, w1, cnt, offs, tok, wl1, nw1, H, nullptr, w2, W2b);
  // GEMM2: Y = H @ W2b^T   all-bf16 (r8 template); N=1024, K=2048
  ffn_gemm_bf<128, DMODEL, DFFN, false, false>
      <<<dim3(WL2MAX * (DMODEL / 128)), dim3(256), 0, stream>>>(
      H, W2b, cnt, offs, tok, wl2, nw2, nullptr, Y);

  combine_kernel<<<dim3(NTOK), dim3(256), 0, stream>>>(x, Y, a_row, chw, wzv, out);
}

// Round 25
// 178.616 us; speedup vs baseline: 1.0188x; 1.0188x over previous
//
#include <hip/hip_runtime.h>
#include <hip/hip_bf16.h>
#include <math.h>

#define NTOK   4096      // B*S
#define DMODEL 1024
#define DFFN   2048
#define NEXP   8         // FFN experts
#define ETOT   12        // total experts (8 FFN + 4 zero)
#define MAXA   8192      // max assignments (NTOK * TOP_K)
#define WL1MAX (MAXA / 128 + NEXP)   // 72 worst-case m-blocks, BM=128
#define WL2MAX (MAXA / 128 + NEXP)   // 72 worst-case m-blocks, BM=128
#define G1GRID (WL1MAX * (DFFN / 128))   // 1152 GEMM1 blocks
#define CVTBLK 2048                      // appended w2-cvt blocks in GEMM1 dispatch

typedef short          bf16x8   __attribute__((ext_vector_type(8)));
typedef float          f32x4    __attribute__((ext_vector_type(4)));
typedef unsigned short ushort8v __attribute__((ext_vector_type(8)));

__device__ __forceinline__ unsigned short f2bf(float f) {
  unsigned int u = __float_as_uint(f);
  unsigned int r = (u + 0x7fffu + ((u >> 16) & 1u)) >> 16;  // RNE
  return (unsigned short)r;
}

__device__ __forceinline__ float bf2f(unsigned short h) {
  return __uint_as_float((unsigned int)h << 16);
}

// scalar bf16 cast — compiler fuses pairs into v_cvt_pk_bf16_f32 (m240)
__device__ __forceinline__ unsigned short f2bfh(float f) {
  __hip_bfloat16 h = __float2bfloat16(f);
  return __builtin_bit_cast(unsigned short, h);
}

#define G2L16(g, l)                                                        \
  __builtin_amdgcn_global_load_lds(                                        \
      (const __attribute__((address_space(1))) void*)(g),                  \
      (__attribute__((address_space(3))) void*)(l), 16, 0, 0)

// ---- routing phase A; also emits Xb (bf16 of x) as it reads x ----------
__launch_bounds__(256)
__global__ void logits_kernel(const float* __restrict__ x,
                              const float* __restrict__ gw,
                              const float* __restrict__ eb,
                              float* __restrict__ logits,
                              unsigned short* __restrict__ Xb) {
  __shared__ float gws[ETOT * DMODEL];   // 48 KB
  int tid = threadIdx.x;
  const float4* gw4 = (const float4*)gw;
  float4* gws4 = (float4*)gws;
  #pragma unroll
  for (int i = 0; i < (ETOT * DMODEL / 4) / 256; i++)
    gws4[tid + i * 256] = gw4[tid + i * 256];
  __syncthreads();

  int sub = tid >> 4;
  int l16 = tid & 15;
  int tok = blockIdx.x * 16 + sub;
  const float4* xr = (const float4*)(x + (size_t)tok * DMODEL);
  ushort4* xbr = (ushort4*)(Xb + (size_t)tok * DMODEL);

  float s[ETOT] = {};
  #pragma unroll
  for (int j = 0; j < 16; j++) {
    float4 xv = xr[l16 + j * 16];
    ushort4 u; u.x = f2bf(xv.x); u.y = f2bf(xv.y); u.z = f2bf(xv.z); u.w = f2bf(xv.w);
    xbr[l16 + j * 16] = u;
    #pragma unroll
    for (int e = 0; e < ETOT; e++) {
      float4 g = gws4[e * (DMODEL / 4) + l16 + j * 16];
      s[e] += xv.x * g.x + xv.y * g.y + xv.z * g.z + xv.w * g.w;
    }
  }
  #pragma unroll
  for (int e = 0; e < ETOT; e++) {
    #pragma unroll
    for (int m = 8; m >= 1; m >>= 1) s[e] += __shfl_xor(s[e], m, 64);
  }
  if (l16 == 0) {
    #pragma unroll
    for (int e = 0; e < ETOT; e++)
      logits[(size_t)tok * ETOT + e] = s[e] + eb[e];
  }
}

// ---------------- routing phase B: top-2, softmax, counts ----------------
__global__ void topk_kernel(const float* __restrict__ logits,
                            int* __restrict__ cnt,
                            int* __restrict__ choice,
                            float* __restrict__ chw,
                            float* __restrict__ wz) {
  int t = blockIdx.x * blockDim.x + threadIdx.x;
  if (t >= NTOK) return;
  const float4* lr = (const float4*)(logits + (size_t)t * ETOT);
  float4 a = lr[0], b = lr[1], c = lr[2];
  float lg[ETOT] = { a.x, a.y, a.z, a.w, b.x, b.y, b.z, b.w, c.x, c.y, c.z, c.w };
  int i1 = 0; float m1 = lg[0];
  #pragma unroll
  for (int e = 1; e < ETOT; e++) if (lg[e] > m1) { m1 = lg[e]; i1 = e; }
  int i2 = -1; float m2 = -3.4e38f;
  #pragma unroll
  for (int e = 0; e < ETOT; e++) { if (e == i1) continue; if (lg[e] > m2) { m2 = lg[e]; i2 = e; } }
  float ex = expf(m2 - m1);
  float w0 = 1.f / (1.f + ex);
  float w1 = ex / (1.f + ex);
  int ee[2] = { i1, i2 };
  float ww[2] = { w0, w1 };
  float z = 0.f;
  #pragma unroll
  for (int k = 0; k < 2; k++) {
    choice[t * 2 + k] = ee[k];
    chw[t * 2 + k]    = ww[k];
    if (ee[k] < NEXP) atomicAdd(&cnt[ee[k]], 1);
    else              z += ww[k];
  }
  wz[t] = z;
}

// -------- scan + dense worklists: (expert|mb<<8) per working m-block ------
__global__ void scan_kernel(const int* __restrict__ cnt,
                            int* __restrict__ offs,
                            int* __restrict__ cursor,
                            int* __restrict__ wl1, int* __restrict__ nw1,
                            int* __restrict__ wl2, int* __restrict__ nw2) {
  if (threadIdx.x == 0) {
    int a = 0;
    for (int e = 0; e < NEXP; e++) { offs[e] = a; cursor[e] = a; a += cnt[e]; }
    int n1 = 0, n2 = 0;
    for (int e = 0; e < NEXP; e++) {
      int c = cnt[e];
      for (int mb = 0; mb * 128 < c; mb++) wl1[n1++] = e | (mb << 8);
      for (int mb = 0; mb * 128 < c; mb++) wl2[n2++] = e | (mb << 8);
    }
    *nw1 = n1; *nw2 = n2;
  }
}

// ---------------- slot assignment (order nondeterministic, values not) ----
__global__ void assign_kernel(const int* __restrict__ choice,
                              int* __restrict__ cursor,
                              int* __restrict__ a_row,
                              int* __restrict__ tok_list) {
  int t = blockIdx.x * blockDim.x + threadIdx.x;
  if (t >= NTOK) return;
  #pragma unroll
  for (int k = 0; k < 2; k++) {
    int e = choice[2 * t + k];
    if (e < NEXP) {
      int pos = atomicAdd(&cursor[e], 1);
      a_row[2 * t + k] = pos;
      tok_list[pos] = t;
    } else {
      a_row[2 * t + k] = -1;
    }
  }
}

// -------- GEMM variant A (r8, replay-proven): all-bf16, async staging -----
// Used for GEMM2: A = H rows, B = W2b (pre-converted bf16). Output bf16.
template <int BM, int NDIM, int KDIM, bool SILU, bool AGATHER>
__launch_bounds__(256)
__global__ void ffn_gemm_bf(const unsigned short* __restrict__ Abf,
                            const unsigned short* __restrict__ Bw,
                            const int* __restrict__ cnt,
                            const int* __restrict__ offs,
                            const int* __restrict__ tok_list,
                            const int* __restrict__ wl,
                            const int* __restrict__ nwork,
                            unsigned short* __restrict__ OutBf) {
  constexpr int NB = NDIM / 128;
  constexpr int MI = BM / 32;
  constexpr int AJ = BM / 64;
  int id = blockIdx.x;
  int nb = id & (NB - 1);
  int wb = id / NB;
  if (wb >= *nwork) return;
  int w  = wl[wb];
  int e  = w & 255;
  int mb = w >> 8;
  int count = cnt[e];
  int m0 = mb * BM;
  int off = offs[e];
  int n0 = nb * 128;
  const unsigned short* B = Bw + (size_t)e * NDIM * KDIM;

  __shared__ unsigned short lA[2][BM * 32];
  __shared__ unsigned short lB[2][128 * 32];

  int tid  = threadIdx.x;
  int lane = tid & 63;
  int wv = tid >> 6;
  int wm = wv >> 1, wn = wv & 1;
  int lr = lane & 15, lk8 = (lane >> 4) * 8;

  int srow = tid >> 2;
  int scol = (tid & 3) * 8;
  const unsigned short* aSrc[AJ];
  const unsigned short* bSrc[2];
  #pragma unroll
  for (int j = 0; j < AJ; j++) {
    int rr = m0 + j * 64 + srow;
    if (rr >= count) rr = count - 1;
    if (AGATHER) aSrc[j] = Abf + (size_t)tok_list[off + rr] * KDIM + scol;
    else         aSrc[j] = Abf + (size_t)(off + rr) * KDIM + scol;
  }
  #pragma unroll
  for (int j = 0; j < 2; j++)
    bSrc[j] = B + (size_t)(n0 + j * 64 + srow) * KDIM + scol;

  f32x4 acc[MI][4] = {};

#define STAGE(b, kk)                                                        \
  do {                                                                      \
    int kb_ = (kk) * 32;                                                    \
    _Pragma("unroll")                                                       \
    for (int j = 0; j < AJ; j++) G2L16(aSrc[j] + kb_, &lA[b][j * 2048 + tid * 8]); \
    _Pragma("unroll")                                                       \
    for (int j = 0; j < 2; j++)  G2L16(bSrc[j] + kb_, &lB[b][j * 2048 + tid * 8]); \
  } while (0)

#define COMPUTE(b)                                                          \
  do {                                                                      \
    bf16x8 af[MI], bq[4];                                                   \
    _Pragma("unroll")                                                       \
    for (int mi = 0; mi < MI; mi++)                                         \
      af[mi] = *(const bf16x8*)&lA[b][(wm * (BM / 2) + mi * 16 + lr) * 32 + lk8]; \
    _Pragma("unroll")                                                       \
    for (int ni = 0; ni < 4; ni++)                                          \
      bq[ni] = *(const bf16x8*)&lB[b][(wn * 64 + ni * 16 + lr) * 32 + lk8]; \
    _Pragma("unroll")                                                       \
    for (int mi = 0; mi < MI; mi++)                                         \
      _Pragma("unroll")                                                     \
      for (int ni = 0; ni < 4; ni++)                                        \
        acc[mi][ni] = __builtin_amdgcn_mfma_f32_16x16x32_bf16(af[mi], bq[ni], acc[mi][ni], 0, 0, 0); \
  } while (0)

  constexpr int NK = KDIM / 32;   // even
  STAGE(0, 0);
  __syncthreads();
  #pragma unroll 1
  for (int kk = 0; kk < NK; kk += 2) {
    if (kk + 1 < NK) STAGE(1, kk + 1);
    COMPUTE(0);
    __syncthreads();
    if (kk + 1 < NK) {
      if (kk + 2 < NK) STAGE(0, kk + 2);
      COMPUTE(1);
      __syncthreads();
    }
  }
#undef STAGE
#undef COMPUTE

  int rb = (lane >> 4) * 4;
  #pragma unroll
  for (int mi = 0; mi < MI; mi++) {
    #pragma unroll
    for (int i = 0; i < 4; i++) {
      int grow = m0 + wm * (BM / 2) + mi * 16 + rb + i;
      if (grow >= count) continue;
      #pragma unroll
      for (int ni = 0; ni < 4; ni++) {
        int gcol = n0 + wn * 64 + ni * 16 + lr;
        float v = acc[mi][ni][i];
        if (SILU) {
          float s = v * __builtin_amdgcn_rcpf(
                        1.f + __builtin_amdgcn_exp2f(-v * 1.44269504088896f));
          OutBf[(size_t)(off + grow) * NDIM + gcol] = f2bf(s);
        } else {
          OutBf[(size_t)(off + grow) * NDIM + gcol] = f2bf(v);
        }
      }
    }
  }
}

// -------- GEMM1 fused (r18/r23, measured): in-kernel w1 convert +
// tail-appended w2-cvt blocks (saves one launch; overlap is partial).
template <int BM, int NDIM, int KDIM, bool SILU, bool AGATHER>
__launch_bounds__(256)
__global__ void ffn_gemm_cv_fused(const unsigned short* __restrict__ Abf,
                                  const float* __restrict__ BwF,
                                  const int* __restrict__ cnt,
                                  const int* __restrict__ offs,
                                  const int* __restrict__ tok_list,
                                  const int* __restrict__ wl,
                                  const int* __restrict__ nwork,
                                  unsigned short* __restrict__ OutBf,
                                  const float* __restrict__ cvt_src,
                                  unsigned short* __restrict__ cvt_dst,
                                  int cvt_n8) {
  constexpr int NB = NDIM / 128;
  constexpr int MI = BM / 32;
  constexpr int AJ = BM / 64;
  int id = blockIdx.x;
  if (id >= G1GRID) {
    // ---- cvt tail: w2 -> W2b, 8 floats/thread/iter, grid-stride ----
    int i0 = (id - G1GRID) * blockDim.x + threadIdx.x;
    int stride = CVTBLK * 256;
    const float4* p = (const float4*)cvt_src;
    for (int i = i0; i < cvt_n8; i += stride) {
      float4 v0 = p[2 * (size_t)i], v1 = p[2 * (size_t)i + 1];
      ushort4 u0, u1;
      u0.x = f2bf(v0.x); u0.y = f2bf(v0.y); u0.z = f2bf(v0.z); u0.w = f2bf(v0.w);
      u1.x = f2bf(v1.x); u1.y = f2bf(v1.y); u1.z = f2bf(v1.z); u1.w = f2bf(v1.w);
      ((ushort4*)cvt_dst)[2 * (size_t)i]     = u0;
      ((ushort4*)cvt_dst)[2 * (size_t)i + 1] = u1;
    }
    return;
  }
  int nb = id & (NB - 1);
  int wb = id / NB;
  if (wb >= *nwork) return;
  int w  = wl[wb];
  int e  = w & 255;
  int mb = w >> 8;
  int count = cnt[e];
  int m0 = mb * BM;
  int off = offs[e];
  int n0 = nb * 128;
  const float* B = BwF + (size_t)e * NDIM * KDIM;

  __shared__ unsigned short lA[2][BM * 32];
  __shared__ unsigned short lB[2][128 * 32];

  int tid  = threadIdx.x;
  int lane = tid & 63;
  int wv = tid >> 6;
  int wm = wv >> 1, wn = wv & 1;
  int lr = lane & 15, lk8 = (lane >> 4) * 8;

  int srow = tid >> 2;
  int scol = (tid & 3) * 8;
  const unsigned short* aSrc[AJ];
  const float* bSrc[2];
  #pragma unroll
  for (int j = 0; j < AJ; j++) {
    int rr = m0 + j * 64 + srow;
    if (rr >= count) rr = count - 1;
    if (AGATHER) aSrc[j] = Abf + (size_t)tok_list[off + rr] * KDIM + scol;
    else         aSrc[j] = Abf + (size_t)(off + rr) * KDIM + scol;
  }
  #pragma unroll
  for (int j = 0; j < 2; j++)
    bSrc[j] = B + (size_t)(n0 + j * 64 + srow) * KDIM + scol;

  f32x4 acc[MI][4] = {};
  f32x4 breg[2][2];

#define STAGEA(b, kk)                                                       \
  do {                                                                      \
    int kb_ = (kk) * 32;                                                    \
    _Pragma("unroll")                                                       \
    for (int j = 0; j < AJ; j++) G2L16(aSrc[j] + kb_, &lA[b][j * 2048 + tid * 8]); \
  } while (0)

#define LOADB(kk)                                                           \
  do {                                                                      \
    int kb_ = (kk) * 32;                                                    \
    _Pragma("unroll")                                                       \
    for (int j = 0; j < 2; j++) {                                           \
      const f32x4* p_ = (const f32x4*)(bSrc[j] + kb_);                      \
      breg[j][0] = p_[0]; breg[j][1] = p_[1];                               \
    }                                                                       \
  } while (0)

#define WRITEB(b)                                                           \
  do {                                                                      \
    _Pragma("unroll")                                                       \
    for (int j = 0; j < 2; j++) {                                           \
      ushort8v u_;                                                          \
      u_[0] = f2bfh(breg[j][0][0]); u_[1] = f2bfh(breg[j][0][1]);           \
      u_[2] = f2bfh(breg[j][0][2]); u_[3] = f2bfh(breg[j][0][3]);           \
      u_[4] = f2bfh(breg[j][1][0]); u_[5] = f2bfh(breg[j][1][1]);           \
      u_[6] = f2bfh(breg[j][1][2]); u_[7] = f2bfh(breg[j][1][3]);           \
      *(ushort8v*)&lB[b][j * 2048 + tid * 8] = u_;                          \
    }                                                                       \
  } while (0)

#define COMPUTE(b)                                                          \
  do {                                                                      \
    bf16x8 af[MI], bq[4];                                                   \
    _Pragma("unroll")                                                       \
    for (int mi = 0; mi < MI; mi++)                                         \
      af[mi] = *(const bf16x8*)&lA[b][(wm * (BM / 2) + mi * 16 + lr) * 32 + lk8]; \
    _Pragma("unroll")                                                       \
    for (int ni = 0; ni < 4; ni++)                                          \
      bq[ni] = *(const bf16x8*)&lB[b][(wn * 64 + ni * 16 + lr) * 32 + lk8]; \
    _Pragma("unroll")                                                       \
    for (int mi = 0; mi < MI; mi++)                                         \
      _Pragma("unroll")                                                     \
      for (int ni = 0; ni < 4; ni++)                                        \
        acc[mi][ni] = __builtin_amdgcn_mfma_f32_16x16x32_bf16(af[mi], bq[ni], acc[mi][ni], 0, 0, 0); \
  } while (0)

  constexpr int NK = KDIM / 32;   // even
  LOADB(0);
  STAGEA(0, 0);
  WRITEB(0);
  __syncthreads();
  #pragma unroll 1
  for (int kk = 0; kk < NK; kk += 2) {
    if (kk + 1 < NK) { LOADB(kk + 1); STAGEA(1, kk + 1); }
    COMPUTE(0);
    if (kk + 1 < NK) WRITEB(1);
    __syncthreads();
    if (kk + 1 < NK) {
      if (kk + 2 < NK) { LOADB(kk + 2); STAGEA(0, kk + 2); }
      COMPUTE(1);
      if (kk + 2 < NK) WRITEB(0);
      __syncthreads();
    }
  }
#undef STAGEA
#undef LOADB
#undef WRITEB
#undef COMPUTE

  int rb = (lane >> 4) * 4;
  #pragma unroll
  for (int mi = 0; mi < MI; mi++) {
    #pragma unroll
    for (int i = 0; i < 4; i++) {
      int grow = m0 + wm * (BM / 2) + mi * 16 + rb + i;
      if (grow >= count) continue;
      #pragma unroll
      for (int ni = 0; ni < 4; ni++) {
        int gcol = n0 + wn * 64 + ni * 16 + lr;
        float v = acc[mi][ni][i];
        if (SILU) {
          float s = v * __builtin_amdgcn_rcpf(
                        1.f + __builtin_amdgcn_exp2f(-v * 1.44269504088896f));
          OutBf[(size_t)(off + grow) * NDIM + gcol] = f2bf(s);
        } else {
          OutBf[(size_t)(off + grow) * NDIM + gcol] = f2bf(v);
        }
      }
    }
  }
}

// ------- final combine: out = wz*x + sum_k w_k * Y[row_k]; Y is bf16 ------
__global__ void combine_kernel(const float* __restrict__ x,
                               const unsigned short* __restrict__ Y,
                               const int* __restrict__ a_row,
                               const float* __restrict__ chw,
                               const float* __restrict__ wz,
                               float* __restrict__ out) {
  int t = blockIdx.x;
  int d = threadIdx.x;   // float4 group index (0..255)
  const float4 xv = *(const float4*)&x[(size_t)t * DMODEL + d * 4];
  float z = wz[t];
  float4 o; o.x = z * xv.x; o.y = z * xv.y; o.z = z * xv.z; o.w = z * xv.w;
  #pragma unroll
  for (int k = 0; k < 2; k++) {
    int r = a_row[2 * t + k];
    if (r >= 0) {
      float w = chw[2 * t + k];
      ushort4 yv = ((const ushort4*)Y)[(size_t)r * (DMODEL / 4) + d];
      o.x += w * bf2f(yv.x); o.y += w * bf2f(yv.y);
      o.z += w * bf2f(yv.z); o.w += w * bf2f(yv.w);
    }
  }
  *(float4*)&out[(size_t)t * DMODEL + d * 4] = o;
}

extern "C" void kernel_launch(void* const* d_in, const int* in_sizes, int n_in,
                              void* d_out, int out_size, void* d_ws, size_t ws_size,
                              hipStream_t stream) {
  const float* x  = (const float*)d_in[0];   // (2,2048,1024)
  const float* gw = (const float*)d_in[1];   // (12,1024)
  const float* eb = (const float*)d_in[2];   // (12,)
  const float* w1 = (const float*)d_in[3];   // (8,2048,1024)
  const float* w2 = (const float*)d_in[4];   // (8,1024,2048)
  float* out = (float*)d_out;

  char* ws = (char*)d_ws;
  size_t o = 0;
  int*   cnt     = (int*)(ws + o);  o += 8 * sizeof(int);
  int*   offs    = (int*)(ws + o);  o += 8 * sizeof(int);
  int*   cursor  = (int*)(ws + o);  o += 8 * sizeof(int);
  int*   nw1     = (int*)(ws + o);  o += sizeof(int);
  int*   nw2     = (int*)(ws + o);  o += sizeof(int);
  o = (o + 255) & ~(size_t)255;
  int*   wl1     = (int*)(ws + o);  o += WL1MAX * sizeof(int);
  int*   wl2     = (int*)(ws + o);  o += WL2MAX * sizeof(int);
  o = (o + 255) & ~(size_t)255;
  int*   choice  = (int*)(ws + o);  o += (size_t)2 * NTOK * sizeof(int);
  float* chw     = (float*)(ws + o); o += (size_t)2 * NTOK * sizeof(float);
  float* wzv     = (float*)(ws + o); o += (size_t)NTOK * sizeof(float);
  int*   a_row   = (int*)(ws + o);  o += (size_t)2 * NTOK * sizeof(int);
  int*   tok     = (int*)(ws + o);  o += (size_t)MAXA * sizeof(int);
  float* logits  = (float*)(ws + o); o += (size_t)NTOK * ETOT * sizeof(float);
  o = (o + 255) & ~(size_t)255;
  unsigned short* Xb  = (unsigned short*)(ws + o); o += (size_t)NTOK * DMODEL * sizeof(unsigned short);
  unsigned short* W2b = (unsigned short*)(ws + o); o += (size_t)NEXP * DMODEL * DFFN * sizeof(unsigned short);
  unsigned short* H   = (unsigned short*)(ws + o); o += (size_t)MAXA * DFFN * sizeof(unsigned short);
  unsigned short* Y   = (unsigned short*)(ws + o); o += (size_t)MAXA * DMODEL * sizeof(unsigned short);

  hipMemsetAsync(cnt, 0, 8 * sizeof(int), stream);

  // logits also emits Xb (bf16 of x). w1 converted inside GEMM1; w2 by
  // GEMM1's appended cvt tail blocks; Y stored bf16 (halves combine read).
  logits_kernel<<<dim3(NTOK / 16), dim3(256), 0, stream>>>(x, gw, eb, logits, Xb);
  topk_kernel<<<dim3(NTOK / 256), dim3(256), 0, stream>>>(logits, cnt, choice, chw, wzv);
  scan_kernel<<<dim3(1), dim3(64), 0, stream>>>(cnt, offs, cursor, wl1, nw1, wl2, nw2);
  assign_kernel<<<dim3(NTOK / 256), dim3(256), 0, stream>>>(choice, cursor, a_row, tok);

  // GEMM1 (+ appended w2 cvt): H = silu(Xb @ bf16(w1)^T); N=2048, K=1024
  ffn_gemm_cv_fused<128, DFFN, DMODEL, true, true>
      <<<dim3(G1GRID + CVTBLK), dim3(256), 0, stream>>>(
      Xb, w1, cnt, offs, tok, wl1, nw1, H,
      w2, W2b, NEXP * DMODEL * DFFN / 8);
  // GEMM2: Y = H @ W2b^T  (bf16 out); N=1024, K=2048
  ffn_gemm_bf<128, DMODEL, DFFN, false, false>
      <<<dim3(WL2MAX * (DMODEL / 128)), dim3(256), 0, stream>>>(
      H, W2b, cnt, offs, tok, wl2, nw2, Y);

  combine_kernel<<<dim3(NTOK), dim3(256), 0, stream>>>(x, Y, a_row, chw, wzv, out);
}